// Round 11
// baseline (299.503 us; speedup 1.0000x reference)
//
#include <hip/hip_runtime.h>

// Problem constants: B=4, S=2048 -> T=8192 tokens; H=512, F=2048, E=8, K=2.
#define T_TOKENS 8192
#define HD 512
#define FD 2048
#define NE 8
#define CAP 8192   // per-expert bucket capacity (worst case all tokens -> one expert)
#define CSTRIDE 32 // counter padding: 32 ints = 128B, one counter per cache line

typedef __attribute__((ext_vector_type(8))) short short8;   // 8 bf16 = 4 VGPRs
typedef __attribute__((ext_vector_type(4))) float f32x4;    // MFMA accumulator

__device__ __forceinline__ ushort f2bf(float f) {
  union { float f; unsigned u; } v; v.f = f;
  unsigned u = v.u;
  return (ushort)((u + 0x7fffu + ((u >> 16) & 1u)) >> 16);  // RNE
}

// async global->LDS, 16B per lane. LDS dest is wave-uniform base + lane*16.
__device__ __forceinline__ void gld16(const ushort* g, ushort* l) {
  __builtin_amdgcn_global_load_lds(
      (const __attribute__((address_space(1))) void*)g,
      (__attribute__((address_space(3))) void*)l, 16, 0, 0);
}

// Fast exact-erf GELU: Abramowitz-Stegun 7.1.26, |erf err| <= 1.5e-7 (exact exp);
// v_rcp_f32 (~1e-6 rel) + __expf keep total error ~1e-6 -- far below bf16 ulp.
__device__ __forceinline__ float gelu_fast(float v) {
  float u = v * 0.70710678118654752f;
  float x = fabsf(u);
  float d = __builtin_fmaf(0.3275911f, x, 1.0f);
  float t;
  asm("v_rcp_f32 %0, %1" : "=v"(t) : "v"(d));
  float y = t * (0.254829592f + t * (-0.284496736f +
            t * (1.421413741f + t * (-1.453152027f + t * 1.061405429f))));
  float erfabs = __builtin_fmaf(-y, __expf(-x * x), 1.0f);
  float erfv = copysignf(erfabs, u);
  return 0.5f * v * (1.0f + erfv);
}

// ---------------- fp32 -> bf16 bulk convert (weights only; x done in router) ---
__global__ void cvt_bf16_2(const float4* __restrict__ s0, ushort4* __restrict__ d0, int c0,
                           const float4* __restrict__ s1, ushort4* __restrict__ d1, int c1) {
  int i = blockIdx.x * blockDim.x + threadIdx.x;
  int st = gridDim.x * blockDim.x;
  int nt = c0 + c1;
  for (; i < nt; i += st) {
    const float4* s; ushort4* d; int j = i;
    if (j < c0) { s = s0; d = d0; }
    else { j -= c0; s = s1; d = d1; }
    float4 v = s[j];
    ushort4 o;
    o.x = f2bf(v.x); o.y = f2bf(v.y); o.z = f2bf(v.z); o.w = f2bf(v.w);
    d[j] = o;
  }
}

// ---------------- router: logits -> softmax -> top2 -> buckets (+ x -> bf16) ---
#define TPW 16
__global__ void router_kernel(const float* __restrict__ x, const float* __restrict__ rw,
                              float* __restrict__ probs_out, float* __restrict__ topk_out,
                              int* __restrict__ counts, int* __restrict__ bucket_tok,
                              float* __restrict__ bucket_w, int4* __restrict__ tok_info,
                              ushort* __restrict__ xb) {
  __shared__ int lcnt[NE];
  __shared__ int lbase[NE];
  __shared__ int ls_e0[64], ls_e1[64], ls_s0[64], ls_s1[64];
  __shared__ float ls_w0[64], ls_w1[64];

  int wave = threadIdx.x >> 6, lane = threadIdx.x & 63;
  if (threadIdx.x < NE) lcnt[threadIdx.x] = 0;
  __syncthreads();

  int tbase = blockIdx.x * 64;
  for (int it = 0; it < TPW; it++) {
    int lt = wave * TPW + it;
    int t = tbase + lt;
    float acc[NE];
#pragma unroll
    for (int e = 0; e < NE; e++) acc[e] = 0.f;
    const float* xr = x + (size_t)t * HD;
    ushort* xbr = xb + (size_t)t * HD;
    for (int c = 0; c < HD; c += 64) {
      float xv = xr[c + lane];
      xbr[c + lane] = f2bf(xv);   // bf16 conversion rides the router's read
#pragma unroll
      for (int e = 0; e < NE; e++) acc[e] += xv * rw[e * HD + c + lane];
    }
#pragma unroll
    for (int e = 0; e < NE; e++) {
#pragma unroll
      for (int s = 32; s > 0; s >>= 1) acc[e] += __shfl_xor(acc[e], s, 64);
    }
    if (lane == 0) {
      float m = acc[0];
#pragma unroll
      for (int e = 1; e < NE; e++) m = fmaxf(m, acc[e]);
      float p[NE], s = 0.f;
#pragma unroll
      for (int e = 0; e < NE; e++) { p[e] = expf(acc[e] - m); s += p[e]; }
      float inv = 1.f / s;
#pragma unroll
      for (int e = 0; e < NE; e++) { p[e] *= inv; probs_out[(size_t)t * NE + e] = p[e]; }
      int i0 = 0;
#pragma unroll
      for (int e = 1; e < NE; e++) if (p[e] > p[i0]) i0 = e;
      int i1 = (i0 == 0) ? 1 : 0;
#pragma unroll
      for (int e = 0; e < NE; e++) if (e != i0 && p[e] > p[i1]) i1 = e;
      float r = 1.f / (p[i0] + p[i1] + 1e-9f);
      topk_out[(size_t)t * 2 + 0] = (float)i0;
      topk_out[(size_t)t * 2 + 1] = (float)i1;
      ls_e0[lt] = i0; ls_e1[lt] = i1;
      ls_w0[lt] = p[i0] * r; ls_w1[lt] = p[i1] * r;
      ls_s0[lt] = atomicAdd(&lcnt[i0], 1);
      ls_s1[lt] = atomicAdd(&lcnt[i1], 1);
    }
  }
  __syncthreads();
  if (threadIdx.x < NE)
    lbase[threadIdx.x] = atomicAdd(&counts[threadIdx.x * CSTRIDE], lcnt[threadIdx.x]);
  __syncthreads();
  if (threadIdx.x < 64) {
    int lt = threadIdx.x, t = tbase + lt;
    int e0 = ls_e0[lt], e1 = ls_e1[lt];
    int g0 = lbase[e0] + ls_s0[lt];
    int g1 = lbase[e1] + ls_s1[lt];
    bucket_tok[e0 * CAP + g0] = t; bucket_w[e0 * CAP + g0] = ls_w0[lt];
    bucket_tok[e1 * CAP + g1] = t; bucket_w[e1 * CAP + g1] = ls_w1[lt];
    tok_info[t] = make_int4(e0, e1, g0, g1);
  }
}

__global__ void scan_kernel(const int* __restrict__ counts, int* __restrict__ offsets) {
  if (threadIdx.x == 0) {
    int o = 0;
#pragma unroll
    for (int e = 0; e < NE; e++) { offsets[e] = o; o += counts[e * CSTRIDE]; }
  }
}

// ---------------- 3-stage pipelined grouped GEMM (128x128, BK=32) -------------
// Schedule identical to the R7/R8 HW-verified kernel (3 buffers, counted
// vmcnt(8), 2 s_barriers/step, full unroll). R9 change: XCD-aware bijective
// grid remap (T1). HW round-robins linear block id across 8 XCDs; the R8 grid
// put the NXB x-sibling blocks (which share an A-tile) on DIFFERENT XCDs, so
// each XCD refetched the same A panel (FC2 FETCH 166MB vs 80MB ideal).
// Remap: id = q*(8*NXB) + xq*8 + r  ->  siblings have id == r (mod 8) = same
// XCD; (y,e) <- q*8+r spreads experts over all XCDs. Pure index change.

__device__ __forceinline__ short8 ldsr32(const ushort* base, int row, int q) {
  int a = row * 64 + q * 16;
  a ^= ((row >> 1) & 3) << 4;
  return *(const short8*)((const char*)base + a);
}

#define VMC(N) asm volatile("s_waitcnt vmcnt(" #N ")" ::: "memory")
#define SB0 __builtin_amdgcn_sched_barrier(0)

#define STG3(KT, SB_) do { \
    ushort* _la = bufA + (SB_) * TU + tid * 8; \
    ushort* _lb = bufB + (SB_) * TU + tid * 8; \
    gld16(aS0 + (KT) * 32, _la); gld16(aS1 + (KT) * 32, _la + 2048); \
    gld16(bS0 + (KT) * 32, _lb); gld16(bS1 + (KT) * 32, _lb + 2048); \
  } while (0)

#define CMP3(RB_) do { \
    const ushort* _As = bufA + (RB_) * TU; \
    const ushort* _Bs = bufB + (RB_) * TU; \
    short8 af[4], bfr[4]; \
    _Pragma("unroll") for (int mi = 0; mi < 4; ++mi) \
      af[mi] = ldsr32(_As, wm * 64 + mi * 16 + l16, q); \
    _Pragma("unroll") for (int nj = 0; nj < 4; ++nj) \
      bfr[nj] = ldsr32(_Bs, wn * 64 + nj * 16 + l16, q); \
    asm volatile("s_waitcnt lgkmcnt(0)" ::: "memory"); SB0; \
    __builtin_amdgcn_s_setprio(1); \
    _Pragma("unroll") for (int mi = 0; mi < 4; ++mi) \
      _Pragma("unroll") for (int nj = 0; nj < 4; ++nj) \
        acc[mi][nj] = __builtin_amdgcn_mfma_f32_16x16x32_bf16(af[mi], bfr[nj], acc[mi][nj], 0, 0, 0); \
    __builtin_amdgcn_s_setprio(0); \
  } while (0)

template <bool IS_FC1, int KD_, int ND_>
__global__ __launch_bounds__(256, 3)
void ffn_gemm_p3(const ushort* __restrict__ Ab, const ushort* __restrict__ Bw,
                 const float* __restrict__ bias, const int* __restrict__ counts,
                 const int* __restrict__ offsets, const int* __restrict__ bucket_tok,
                 const float* __restrict__ bucket_w, ushort* __restrict__ Aout,
                 float* __restrict__ Yout) {
  constexpr int TU = 128 * 32;   // ushorts per buffer (8 KB)
  constexpr int NK = KD_ >> 5;   // FC1: 16, FC2: 64
  constexpr int NXB = ND_ / 128; // x-blocks per (y,e): FC1 16, FC2 4
  constexpr int XSH = (NXB == 16) ? 4 : 2;  // log2(NXB)
  static_assert(NK >= 3, "pipeline needs >= 3 K-steps");

  // XCD-aware bijective remap: id = q*(8*NXB) + xq*8 + r
  int id = blockIdx.x;
  int r = id & 7;
  int xq = (id >> 3) & (NXB - 1);
  int qg = id >> (3 + XSH);            // [0, 64)
  int yz = qg * 8 + r;                 // [0, 512)
  int ybl = yz & 63;                   // y block [0, CAP/128)
  int e = yz >> 6;                     // expert

  int cnt = counts[e * CSTRIDE];
  int m0 = ybl * 128;
  if (m0 >= cnt) return;
  int n0 = xq * 128;
  int off = offsets[e];

  extern __shared__ ushort smem[];   // 48 KiB: A0 A1 A2 B0 B1 B2
  ushort* bufA = smem;
  ushort* bufB = smem + 3 * TU;

  int tid = threadIdx.x;
  int lid = tid & 63, w = tid >> 6;
  int wm = w >> 1, wn = w & 1;                 // 2x2 waves, per-wave 64x64
  int q = lid >> 4, l16 = lid & 15;
  int r0 = tid >> 2;                           // staging row 0..63 (4 lanes/row)
  int colElem = (((tid & 3) ^ ((r0 >> 1) & 3)) << 3);  // inverse-swizzled col

  const ushort *aS0, *aS1, *bS0, *bS1;
  {
    int rA0 = min(m0 + r0, cnt - 1);
    int rA1 = min(m0 + 64 + r0, cnt - 1);
    int t0 = IS_FC1 ? bucket_tok[e * CAP + rA0] : (off + rA0);
    int t1 = IS_FC1 ? bucket_tok[e * CAP + rA1] : (off + rA1);
    aS0 = Ab + (size_t)t0 * KD_ + colElem;
    aS1 = Ab + (size_t)t1 * KD_ + colElem;
    bS0 = Bw + ((size_t)e * ND_ + n0 + r0) * KD_ + colElem;
    bS1 = Bw + ((size_t)e * ND_ + n0 + 64 + r0) * KD_ + colElem;
  }

  f32x4 acc[4][4] = {};

  STG3(0, 0); STG3(1, 1);
#pragma unroll
  for (int k = 0; k < NK - 2; ++k) {
    STG3(k + 2, (k + 2) % 3); SB0;
    VMC(8); SB0;                       // tile k fully resident (own loads)
    __builtin_amdgcn_s_barrier(); SB0; // all waves' tile-k loads in LDS
    CMP3(k % 3);
    SB0; __builtin_amdgcn_s_barrier(); // all waves' reads retired -> buf free
  }
  VMC(4); SB0; __builtin_amdgcn_s_barrier(); SB0;
  CMP3((NK - 2) % 3); SB0; __builtin_amdgcn_s_barrier();
  VMC(0); SB0; __builtin_amdgcn_s_barrier(); SB0;
  CMP3((NK - 1) % 3); SB0; __builtin_amdgcn_s_barrier();

  // ---- epilogue via LDS round-trip (layout verified R4/R5/R7/R8) ----
  float bcol[4];
#pragma unroll
  for (int j = 0; j < 4; ++j)
    bcol[j] = bias[(size_t)e * ND_ + n0 + wn * 64 + j * 16 + l16];

  if (IS_FC1) {
    ushort* Ct = smem;  // [32][136] bf16
#pragma unroll
    for (int i = 0; i < 4; i++) {
      __syncthreads();
#pragma unroll
      for (int j = 0; j < 4; j++)
#pragma unroll
        for (int r2 = 0; r2 < 4; r2++) {
          float v = acc[i][j][r2] + bcol[j];
          Ct[(wm * 16 + q * 4 + r2) * 136 + wn * 64 + j * 16 + l16] = f2bf(gelu_fast(v));
        }
      __syncthreads();
#pragma unroll
      for (int u = 0; u < 2; u++) {
        int c = tid + u * 256;            // 512 chunks of 8 bf16
        int ml = c >> 4, cc = c & 15;
        int gm = m0 + (ml >> 4) * 64 + i * 16 + (ml & 15);
        if (gm < cnt)
          *(uint4*)&Aout[(size_t)(off + gm) * ND_ + n0 + cc * 8] =
              *(const uint4*)&Ct[ml * 136 + cc * 8];
      }
    }
  } else {
    float* Cf = (float*)smem;  // [32][132] fp32
#pragma unroll
    for (int i = 0; i < 4; i++) {
      __syncthreads();
#pragma unroll
      for (int r2 = 0; r2 < 4; r2++) {
        int gm = m0 + wm * 64 + i * 16 + q * 4 + r2;
        float wgt = bucket_w[e * CAP + min(gm, cnt - 1)];
#pragma unroll
        for (int j = 0; j < 4; j++)
          Cf[(wm * 16 + q * 4 + r2) * 132 + wn * 64 + j * 16 + l16] = wgt * (acc[i][j][r2] + bcol[j]);
      }
      __syncthreads();
#pragma unroll
      for (int u = 0; u < 4; u++) {
        int c = tid + u * 256;            // 1024 chunks of 4 floats
        int ml = c >> 5, cc = c & 31;
        int gm = m0 + (ml >> 4) * 64 + i * 16 + (ml & 15);
        if (gm < cnt)
          *(float4*)&Yout[(size_t)(off + gm) * ND_ + n0 + cc * 4] =
              *(const float4*)&Cf[ml * 132 + cc * 4];
      }
    }
  }
}

// ---------------- combine: out[t] = Y[row(e0,s0)] + Y[row(e1,s1)] ----------------
__global__ void combine_kernel(const float4* __restrict__ Y, const int4* __restrict__ tok_info,
                               const int* __restrict__ offsets, float4* __restrict__ out) {
  int t = blockIdx.x;
  int4 ti = tok_info[t];
  int g0 = offsets[ti.x] + ti.z;
  int g1 = offsets[ti.y] + ti.w;
  int i = threadIdx.x;  // 128 threads, H/4 = 128 float4 per row
  float4 a = Y[(size_t)g0 * (HD / 4) + i];
  float4 b = Y[(size_t)g1 * (HD / 4) + i];
  out[(size_t)t * (HD / 4) + i] = make_float4(a.x + b.x, a.y + b.y, a.z + b.z, a.w + b.w);
}

extern "C" void kernel_launch(void* const* d_in, const int* in_sizes, int n_in,
                              void* d_out, int out_size, void* d_ws, size_t ws_size,
                              hipStream_t stream) {
  const float* x    = (const float*)d_in[0];
  const float* rw   = (const float*)d_in[1];
  const float* fc1w = (const float*)d_in[2];
  const float* fc1b = (const float*)d_in[3];
  const float* fc2w = (const float*)d_in[4];
  const float* fc2b = (const float*)d_in[5];

  float* out   = (float*)d_out;
  float* probs = out + (size_t)T_TOKENS * HD;
  float* topk  = probs + (size_t)T_TOKENS * NE;

  static bool attr_done = false;
  if (!attr_done) {
    (void)hipFuncSetAttribute((const void*)&ffn_gemm_p3<true, HD, FD>,
                              hipFuncAttributeMaxDynamicSharedMemorySize, 49152);
    (void)hipFuncSetAttribute((const void*)&ffn_gemm_p3<false, FD, HD>,
                              hipFuncAttributeMaxDynamicSharedMemorySize, 49152);
    attr_done = true;
  }

  char* p = (char*)d_ws;
  auto carve = [&](size_t bytes) { char* r = p; p += (bytes + 255) & ~(size_t)255; return r; };
  int*    counts     = (int*)carve(NE * CSTRIDE * sizeof(int));
  int*    offsets    = (int*)carve(NE * sizeof(int));
  int*    bucket_tok = (int*)carve((size_t)NE * CAP * sizeof(int));
  float*  bucket_w   = (float*)carve((size_t)NE * CAP * sizeof(float));
  int4*   tok_info   = (int4*)carve((size_t)T_TOKENS * sizeof(int4));
  ushort* xb   = (ushort*)carve((size_t)T_TOKENS * HD * 2);
  ushort* w1b  = (ushort*)carve((size_t)NE * FD * HD * 2);
  ushort* w2b  = (ushort*)carve((size_t)NE * HD * FD * 2);
  ushort* Abuf = (ushort*)carve((size_t)T_TOKENS * 2 * FD * 2);  // compact GELU out, bf16
  float*  Y    = (float*)carve((size_t)T_TOKENS * 2 * HD * 4);   // gated FC2 rows, fp32

  hipMemsetAsync(counts, 0, NE * CSTRIDE * sizeof(int), stream);
  cvt_bf16_2<<<4096, 256, 0, stream>>>(
      (const float4*)fc1w, (ushort4*)w1b, NE * FD * HD / 4,
      (const float4*)fc2w, (ushort4*)w2b, NE * HD * FD / 4);
  router_kernel<<<T_TOKENS / 64, 256, 0, stream>>>(x, rw, probs, topk, counts, bucket_tok,
                                                   bucket_w, tok_info, xb);
  scan_kernel<<<1, 64, 0, stream>>>(counts, offsets);

  // 1-D grids with XCD-aware remap inside the kernel.
  // FC1: NXB=16 -> 16*64*8 = 8192 blocks; FC2: NXB=4 -> 4*64*8 = 2048 blocks.
  ffn_gemm_p3<true, HD, FD><<<16 * 64 * 8, 256, 49152, stream>>>(
      xb, w1b, fc1b, counts, offsets, bucket_tok, bucket_w, Abuf, nullptr);
  ffn_gemm_p3<false, FD, HD><<<4 * 64 * 8, 256, 49152, stream>>>(
      Abuf, w2b, fc2b, counts, offsets, bucket_tok, bucket_w, nullptr, Y);

  combine_kernel<<<T_TOKENS, 128, 0, stream>>>((const float4*)Y, tok_info, offsets, (float4*)out);
}